// Round 2
// baseline (395.811 us; speedup 1.0000x reference)
//
#include <hip/hip_runtime.h>
#include <hip/hip_bf16.h>

typedef __bf16 bf16x8 __attribute__((ext_vector_type(8)));
typedef __bf16 bf16x2 __attribute__((ext_vector_type(2)));
typedef float f32x4 __attribute__((ext_vector_type(4)));

// Kernel 1: prototypes f32 -> bf16 (RNE), and ysq[c] = ||proto_c||^2 in f32.
// One wave per class (D=128 -> 2 floats per lane).
__global__ void dce_prep(const float* __restrict__ protos,
                         unsigned short* __restrict__ protob,
                         float* __restrict__ ysq) {
    int c = blockIdx.x;
    int lane = threadIdx.x;  // 0..63
    float2 f = ((const float2*)(protos))[c * 64 + lane];
    bf16x2 h;
    h.x = (__bf16)f.x;
    h.y = (__bf16)f.y;
    ((bf16x2*)protob)[c * 64 + lane] = h;
    float xs = f.x * f.x + f.y * f.y;
#pragma unroll
    for (int d = 1; d < 64; d <<= 1) xs += __shfl_xor(xs, d);
    if (lane == 0) ysq[c] = xs;
}

// Kernel 2: fused  -sqrt(||x||^2+||y||^2-2xy)  ->  log-softmax-NLL partial per block.
// Block = 256 threads = 4 waves; each wave owns 64 rows (4 MFMA M-frags),
// loops over all C classes in tiles of 16 (4x mfma_f32_16x16x32_bf16 per M-frag).
// Fixed softmax reference max = 0 (logits <= 0 always): l = sum exp(-dist),
// nll = dist_label + ln(l).
__global__ __launch_bounds__(256) void dce_main(
    const float* __restrict__ feats,
    const unsigned short* __restrict__ protob,
    const float* __restrict__ ysq,
    const int* __restrict__ labels,
    float* __restrict__ partials, int C) {
    const int lane = threadIdx.x & 63;
    const int w = threadIdx.x >> 6;
    const int rbase = blockIdx.x * 256 + w * 64;
    const int lr = lane & 15;   // col / row-within-Mfrag selector
    const int lg = lane >> 4;   // k-group

    // ---- Load A fragments (rows rbase..rbase+63), exact-f32 row norms ----
    bf16x8 a[4][4];
    float rowxs[4];
    const float4* f4 = (const float4*)feats;
#pragma unroll
    for (int m = 0; m < 4; ++m) {
        int r = rbase + m * 16 + lr;
        float xs = 0.f;
#pragma unroll
        for (int kk = 0; kk < 4; ++kk) {
            int idx = r * 32 + kk * 8 + lg * 2;  // float4 index: r*128 + kk*32 + lg*8 floats
            float4 lo = f4[idx];
            float4 hi = f4[idx + 1];
            bf16x8 v;
            v[0] = (__bf16)lo.x; v[1] = (__bf16)lo.y; v[2] = (__bf16)lo.z; v[3] = (__bf16)lo.w;
            v[4] = (__bf16)hi.x; v[5] = (__bf16)hi.y; v[6] = (__bf16)hi.z; v[7] = (__bf16)hi.w;
            a[m][kk] = v;
            xs += lo.x * lo.x + lo.y * lo.y + lo.z * lo.z + lo.w * lo.w +
                  hi.x * hi.x + hi.y * hi.y + hi.z * hi.z + hi.w * hi.w;
        }
        xs += __shfl_xor(xs, 16);
        xs += __shfl_xor(xs, 32);
        rowxs[m] = xs;  // ||feat_{rbase+m*16+lr}||^2, replicated over lg
    }

    // Redistribute ||x||^2 and labels to the C/D fragment layout:
    // acc element (m, reg) at this lane covers row m*16 + lg*4 + reg, col = tile*16 + lr.
    float xsq[4][4];
    int lab[4][4];
#pragma unroll
    for (int m = 0; m < 4; ++m)
#pragma unroll
        for (int reg = 0; reg < 4; ++reg) {
            xsq[m][reg] = __shfl(rowxs[m], lg * 4 + reg);
            lab[m][reg] = labels[rbase + m * 16 + lg * 4 + reg];
        }

    float lacc[4][4];
    float labd[4][4];
#pragma unroll
    for (int m = 0; m < 4; ++m)
#pragma unroll
        for (int reg = 0; reg < 4; ++reg) { lacc[m][reg] = 0.f; labd[m][reg] = 0.f; }

    const bf16x8* bp = (const bf16x8*)protob;
    const int nt = C >> 4;
    for (int ct = 0; ct < nt; ++ct) {
        const int c = (ct << 4) + lr;  // this lane's class column
        bf16x8 b[4];
#pragma unroll
        for (int kk = 0; kk < 4; ++kk) b[kk] = bp[c * 16 + kk * 4 + lg];
        const float yq = ysq[c];
#pragma unroll
        for (int m = 0; m < 4; ++m) {
            f32x4 acc = {0.f, 0.f, 0.f, 0.f};
#pragma unroll
            for (int kk = 0; kk < 4; ++kk)
                acc = __builtin_amdgcn_mfma_f32_16x16x32_bf16(a[m][kk], b[kk], acc, 0, 0, 0);
#pragma unroll
            for (int reg = 0; reg < 4; ++reg) {
                float d = fmaf(-2.f, acc[reg], xsq[m][reg] + yq);
                d = fmaxf(d, 0.f);
                float dist = sqrtf(d);
                lacc[m][reg] += __expf(-dist);
                labd[m][reg] += (c == lab[m][reg]) ? dist : 0.f;
            }
        }
    }

    // ---- Reduce: per row, sum l and label-dist over the 16 column-lanes ----
    float s = 0.f;
#pragma unroll
    for (int m = 0; m < 4; ++m)
#pragma unroll
        for (int reg = 0; reg < 4; ++reg) {
            float l = lacc[m][reg];
            float t = labd[m][reg];
#pragma unroll
            for (int d = 1; d < 16; d <<= 1) {
                l += __shfl_xor(l, d);
                t += __shfl_xor(t, d);
            }
            s += t + __logf(l);  // nll = dist_label + ln(sum exp(-dist))
        }
    // s is uniform within each 16-lane group; sum the 4 groups:
    s += __shfl_xor(s, 16);
    s += __shfl_xor(s, 32);

    __shared__ float red[4];
    if (lane == 0) red[w] = s;
    __syncthreads();
    if (threadIdx.x == 0) partials[blockIdx.x] = red[0] + red[1] + red[2] + red[3];
}

// Kernel 3: deterministic reduction of per-block partials -> mean.
__global__ void dce_finish(const float* __restrict__ partials,
                           float* __restrict__ out, int nblocks, float invN) {
    int tid = threadIdx.x;  // 256
    float s = 0.f;
    for (int i = tid; i < nblocks; i += 256) s += partials[i];
#pragma unroll
    for (int d = 1; d < 64; d <<= 1) s += __shfl_xor(s, d);
    __shared__ float red[4];
    if ((tid & 63) == 0) red[tid >> 6] = s;
    __syncthreads();
    if (tid == 0) out[0] = (red[0] + red[1] + red[2] + red[3]) * invN;
}

extern "C" void kernel_launch(void* const* d_in, const int* in_sizes, int n_in,
                              void* d_out, int out_size, void* d_ws, size_t ws_size,
                              hipStream_t stream) {
    const float* feats = (const float*)d_in[0];
    const float* protos = (const float*)d_in[1];
    const int* labels = (const int*)d_in[2];
    const int N = in_sizes[2];          // 262144
    const int C = in_sizes[1] / 128;    // 1024
    float* out = (float*)d_out;

    // Workspace layout: [proto_bf16: C*128*2B][ysq: C*4B][partials: nblocks*4B]
    unsigned short* protob = (unsigned short*)d_ws;
    float* ysq = (float*)((char*)d_ws + (size_t)C * 128 * 2);
    float* partials = ysq + C;
    const int nblocks = N / 256;

    dce_prep<<<C, 64, 0, stream>>>(protos, protob, ysq);
    dce_main<<<nblocks, 256, 0, stream>>>(feats, protob, ysq, labels, partials, C);
    dce_finish<<<1, 256, 0, stream>>>(partials, out, nblocks, 1.0f / (float)N);
}

// Round 3
// 141.346 us; speedup vs baseline: 2.8003x; 2.8003x over previous
//
#include <hip/hip_runtime.h>
#include <hip/hip_bf16.h>

typedef __bf16 bf16x8 __attribute__((ext_vector_type(8)));
typedef __bf16 bf16x2 __attribute__((ext_vector_type(2)));
typedef float f32x4 __attribute__((ext_vector_type(4)));

#define K2f 2.0813689810056077f   // log2(e)^2
#define LN2f 0.6931471805599453f

// Kernel 1: prototypes f32 -> bf16 stored in MFMA B-fragment order, plus
// ysq2[c] = ||proto_c||^2 * log2(e)^2.
// Fragment order: element e of class c, dim d (d = kk*32 + lg*8 + e) lives at
// bf16 offset ((ct*4+kk)*64 + lg*16 + (c&15))*8 + e, ct = c>>4.
// Main loop then loads b[kk] = vec8[(ct*4+kk)*64 + lane] fully coalesced.
__global__ void dce_prep(const float* __restrict__ protos,
                         unsigned short* __restrict__ bpf,
                         float* __restrict__ ysq2) {
    int c = blockIdx.x;
    int lane = threadIdx.x;  // 0..63, covers dims 2*lane, 2*lane+1
    float2 f = ((const float2*)(protos))[c * 64 + lane];
    int d0 = lane * 2;
    int kk = d0 >> 5, sub = d0 & 31, lg = sub >> 3, e = sub & 7;
    size_t o = (((size_t)((c >> 4) * 4 + kk) * 64) + lg * 16 + (c & 15)) * 8 + e;
    bf16x2 h;
    h.x = (__bf16)f.x;
    h.y = (__bf16)f.y;
    *(bf16x2*)(bpf + o) = h;
    float xs = f.x * f.x + f.y * f.y;
#pragma unroll
    for (int d = 1; d < 64; d <<= 1) xs += __shfl_xor(xs, d);
    if (lane == 0) ysq2[c] = xs * K2f;
}

// Kernel 2: fused distance-softmax-NLL.
// Block = 256 threads = 4 waves; wave owns 64 rows (4 M-frags of 16).
// Phase 1: per-thread exact-f32 label distance (also yields ||x||^2).
// Phase 2: bf16 MFMA over all C classes, epilogue = exp2(-sqrt(scaled)) only.
// logits <= 0 always  ->  softmax max fixed at 0, no online max needed:
//   nll = dist_label + ln2 * log2( sum_c 2^(-log2e * dist_c) ).
__global__ __launch_bounds__(256, 4) void dce_main(
    const float* __restrict__ feats,
    const float* __restrict__ protos,
    const unsigned short* __restrict__ bpf,
    const float* __restrict__ ysq2,
    const int* __restrict__ labels,
    float* __restrict__ partials, int C) {
    const int tid = threadIdx.x;
    const int lane = tid & 63;
    const int w = tid >> 6;
    const int row0 = blockIdx.x * 256;
    const int rbase = row0 + w * 64;
    const int lr = lane & 15;
    const int lg = lane >> 4;

    // ---- Phase 1: exact f32 label distance for row (row0 + tid) ----
    const int lab = labels[row0 + tid];
    const float4* fx = (const float4*)(feats + (size_t)(row0 + tid) * 128);
    const float4* px = (const float4*)(protos + (size_t)lab * 128);
    float xx = 0.f, yy = 0.f, xy = 0.f;
#pragma unroll 8
    for (int i = 0; i < 32; ++i) {
        float4 f = fx[i], p = px[i];
        xx = fmaf(f.x, f.x, fmaf(f.y, f.y, fmaf(f.z, f.z, fmaf(f.w, f.w, xx))));
        yy = fmaf(p.x, p.x, fmaf(p.y, p.y, fmaf(p.z, p.z, fmaf(p.w, p.w, yy))));
        xy = fmaf(f.x, p.x, fmaf(f.y, p.y, fmaf(f.z, p.z, fmaf(f.w, p.w, xy))));
    }
    const float ld = __builtin_amdgcn_sqrtf(fmaxf(fmaf(-2.f, xy, xx + yy), 0.f));

    // ---- Load A fragments (rows rbase..rbase+63) ----
    bf16x8 a[4][4];
    const float4* f4 = (const float4*)feats;
#pragma unroll
    for (int m = 0; m < 4; ++m) {
        int r = rbase + m * 16 + lr;
#pragma unroll
        for (int kk = 0; kk < 4; ++kk) {
            int idx = r * 32 + kk * 8 + lg * 2;
            float4 lo = f4[idx];
            float4 hi = f4[idx + 1];
            bf16x8 v;
            v[0] = (__bf16)lo.x; v[1] = (__bf16)lo.y; v[2] = (__bf16)lo.z; v[3] = (__bf16)lo.w;
            v[4] = (__bf16)hi.x; v[5] = (__bf16)hi.y; v[6] = (__bf16)hi.z; v[7] = (__bf16)hi.w;
            a[m][kk] = v;
        }
    }

    // ||x||^2 (scaled) arranged to the C/D layout: element (m,reg) covers
    // row m*16 + lg*4 + reg -> pull from that thread's exact xx.
    float xsqs[4][4];
#pragma unroll
    for (int m = 0; m < 4; ++m)
#pragma unroll
        for (int reg = 0; reg < 4; ++reg)
            xsqs[m][reg] = K2f * __shfl(xx, m * 16 + lg * 4 + reg);

    float lacc[4][4];
#pragma unroll
    for (int m = 0; m < 4; ++m)
#pragma unroll
        for (int reg = 0; reg < 4; ++reg) lacc[m][reg] = 0.f;

    // ---- Phase 2: main fused loop over class tiles of 16 ----
    const bf16x8* bv = (const bf16x8*)bpf;
    const int nt = C >> 4;
    for (int ct = 0; ct < nt; ++ct) {
        bf16x8 b[4];
#pragma unroll
        for (int kk = 0; kk < 4; ++kk) b[kk] = bv[(ct * 4 + kk) * 64 + lane];
        const float yq2 = ysq2[ct * 16 + lr];
#pragma unroll
        for (int m = 0; m < 4; ++m) {
            f32x4 acc = {0.f, 0.f, 0.f, 0.f};
#pragma unroll
            for (int kk = 0; kk < 4; ++kk)
                acc = __builtin_amdgcn_mfma_f32_16x16x32_bf16(a[m][kk], b[kk], acc, 0, 0, 0);
#pragma unroll
            for (int reg = 0; reg < 4; ++reg) {
                float d = fmaf(-2.f * K2f, acc[reg], xsqs[m][reg] + yq2);
                d = fmaxf(d, 0.f);
                float s = __builtin_amdgcn_sqrtf(d);     // = log2e * dist
                lacc[m][reg] += __builtin_amdgcn_exp2f(-s);
            }
        }
    }

    // ---- Reduce: sum l over the 16 column-lanes per row, add label dist ----
    float ssum = 0.f;
#pragma unroll
    for (int m = 0; m < 4; ++m)
#pragma unroll
        for (int reg = 0; reg < 4; ++reg) {
            float l = lacc[m][reg];
            l += __shfl_xor(l, 1);
            l += __shfl_xor(l, 2);
            l += __shfl_xor(l, 4);
            l += __shfl_xor(l, 8);
            float ldv = __shfl(ld, m * 16 + lg * 4 + reg);
            if (lr == 0) ssum += ldv + LN2f * __builtin_amdgcn_logf(l);
        }
    ssum += __shfl_xor(ssum, 16);
    ssum += __shfl_xor(ssum, 32);

    __shared__ float red[4];
    if (lane == 0) red[w] = ssum;
    __syncthreads();
    if (tid == 0) partials[blockIdx.x] = red[0] + red[1] + red[2] + red[3];
}

// Kernel 3: deterministic reduction of per-block partials -> mean.
__global__ void dce_finish(const float* __restrict__ partials,
                           float* __restrict__ out, int nblocks, float invN) {
    int tid = threadIdx.x;  // 256
    float s = 0.f;
    for (int i = tid; i < nblocks; i += 256) s += partials[i];
#pragma unroll
    for (int d = 1; d < 64; d <<= 1) s += __shfl_xor(s, d);
    __shared__ float red[4];
    if ((tid & 63) == 0) red[tid >> 6] = s;
    __syncthreads();
    if (tid == 0) out[0] = (red[0] + red[1] + red[2] + red[3]) * invN;
}

extern "C" void kernel_launch(void* const* d_in, const int* in_sizes, int n_in,
                              void* d_out, int out_size, void* d_ws, size_t ws_size,
                              hipStream_t stream) {
    const float* feats = (const float*)d_in[0];
    const float* protos = (const float*)d_in[1];
    const int* labels = (const int*)d_in[2];
    const int N = in_sizes[2];          // 262144
    const int C = in_sizes[1] / 128;    // 1024
    float* out = (float*)d_out;

    // Workspace: [bpf: C*128*2B][ysq2: C*4B][partials: N/256*4B]
    unsigned short* bpf = (unsigned short*)d_ws;
    float* ysq2 = (float*)((char*)d_ws + (size_t)C * 128 * 2);
    float* partials = ysq2 + C;
    const int nblocks = N / 256;

    dce_prep<<<C, 64, 0, stream>>>(protos, bpf, ysq2);
    dce_main<<<nblocks, 256, 0, stream>>>(feats, protos, bpf, ysq2, labels, partials, C);
    dce_finish<<<1, 256, 0, stream>>>(partials, out, nblocks, 1.0f / (float)N);
}